// Round 5
// baseline (1639.825 us; speedup 1.0000x reference)
//
#include <hip/hip_runtime.h>

#define F_IN 128
#define F_HID 16
#define N_CLS 10
#define TILE 16384          // edges per binning tile
#define RB 128              // nodes per bucket (dst >> 7)
#define MAXBUK 1024

// ================= binning: per-tile bucket histogram =================

__global__ __launch_bounds__(256) void k_tilehist(const int* __restrict__ dst,
                                                  int* __restrict__ th, int ne, int nbuk) {
    __shared__ int h[MAXBUK];
    int t = blockIdx.x;
    for (int i = threadIdx.x; i < nbuk; i += 256) h[i] = 0;
    __syncthreads();
    int e0 = t * TILE, e1 = min(e0 + TILE, ne);
    for (int i = e0 + threadIdx.x; i < e1; i += 256)
        atomicAdd(&h[dst[i] >> 7], 1);
    __syncthreads();
    for (int i = threadIdx.x; i < nbuk; i += 256) th[t * nbuk + i] = h[i];
}

// ================= binning: per-bucket scan across tiles =================
// th[t][b] -> exclusive prefix within bucket b; totals[b] = bucket size

__global__ __launch_bounds__(256) void k_colscan(int* __restrict__ th,
                                                 int* __restrict__ totals, int nt, int nbuk) {
    int b = blockIdx.x;
    __shared__ int sm[256];
    __shared__ int s_run;
    if (threadIdx.x == 0) s_run = 0;
    __syncthreads();
    for (int t0 = 0; t0 < nt; t0 += 256) {
        int t = t0 + threadIdx.x;
        int v = (t < nt) ? th[t * nbuk + b] : 0;
        sm[threadIdx.x] = v;
        __syncthreads();
        int acc = v;
        for (int d = 1; d < 256; d <<= 1) {
            int add = (threadIdx.x >= d) ? sm[threadIdx.x - d] : 0;
            __syncthreads();
            acc += add;
            sm[threadIdx.x] = acc;
            __syncthreads();
        }
        int run = s_run;
        if (t < nt) th[t * nbuk + b] = run + acc - v;   // exclusive within bucket
        __syncthreads();
        if (threadIdx.x == 255) s_run = run + acc;      // acc@255 = chunk total
        __syncthreads();
    }
    if (threadIdx.x == 0) totals[b] = s_run;
}

// single-block exclusive scan of totals -> bases[0..nbuk], bases[nbuk]=ne

__global__ __launch_bounds__(1024) void k_bscan(const int* __restrict__ totals,
                                                int* __restrict__ bases, int nb) {
    __shared__ int sm[1024];
    int t = threadIdx.x;
    int v = (t < nb) ? totals[t] : 0;
    sm[t] = v;
    __syncthreads();
    int acc = v;
    for (int d = 1; d < 1024; d <<= 1) {
        int add = (t >= d) ? sm[t - d] : 0;
        __syncthreads();
        acc += add;
        sm[t] = acc;
        __syncthreads();
    }
    if (t < nb) bases[t] = acc - v;
    if (t == nb - 1) bases[nb] = acc;
}

// ================= binning: scatter into bucket-grouped array =================
// pack = (dst_local << 20) | src   (src < 2^20, dst_local < 128)

__global__ __launch_bounds__(256) void k_tilescatter(const int* __restrict__ src,
                                                     const int* __restrict__ dst,
                                                     const int* __restrict__ th,
                                                     const int* __restrict__ bases,
                                                     int* __restrict__ csr, int ne, int nbuk) {
    __shared__ int cur[MAXBUK];
    int t = blockIdx.x;
    for (int i = threadIdx.x; i < nbuk; i += 256)
        cur[i] = bases[i] + th[t * nbuk + i];
    __syncthreads();
    int e0 = t * TILE, e1 = min(e0 + TILE, ne);
    for (int i = e0 + threadIdx.x; i < e1; i += 256) {
        int d = dst[i], s = src[i];
        int b = d >> 7;
        int p = atomicAdd(&cur[b], 1);
        csr[p] = ((d & 127) << 20) | s;
    }
}

// ================= degrees from binned csr -> dinv =================

__global__ __launch_bounds__(256) void k_dinvcsr(const int* __restrict__ csr,
                                                 const int* __restrict__ bases,
                                                 float* __restrict__ dinv, int n) {
    __shared__ int cnt[RB];
    if (threadIdx.x < RB) cnt[threadIdx.x] = 0;
    __syncthreads();
    int bu = blockIdx.x;
    int e0 = bases[bu], e1 = bases[bu + 1];
    for (int i = e0 + threadIdx.x; i < e1; i += 256)
        atomicAdd(&cnt[csr[i] >> 20], 1);
    __syncthreads();
    if (threadIdx.x < RB) {
        int node = (bu << 7) + threadIdx.x;
        if (node < n) dinv[node] = rsqrtf((float)(cnt[threadIdx.x] + 1));  // +1 self-loop
    }
}

// ================= layer 1 linear (pre-scaled): h1s = (x @ W1) * dinv =================
// one thread per node; W1 staged in LDS; x row read as float4.

__global__ __launch_bounds__(256) void k_gemm1(const float* __restrict__ x,
                                               const float* __restrict__ W1,
                                               const float* __restrict__ dinv,
                                               float* __restrict__ h1s, int n) {
    __shared__ float Ws[F_IN * F_HID];  // [k][f], 8 KB
    for (int i = threadIdx.x; i < F_IN * F_HID; i += 256) Ws[i] = W1[i];
    __syncthreads();
    int node = blockIdx.x * 256 + threadIdx.x;
    if (node >= n) return;
    const float4* xr = (const float4*)(x + (size_t)node * F_IN);
    float acc[16];
#pragma unroll
    for (int f = 0; f < 16; ++f) acc[f] = 0.f;
#pragma unroll 8
    for (int k4 = 0; k4 < 32; ++k4) {
        float4 xv = xr[k4];
        float xc[4] = {xv.x, xv.y, xv.z, xv.w};
#pragma unroll
        for (int kk = 0; kk < 4; ++kk) {
            int k = k4 * 4 + kk;
            const float4* wr = (const float4*)&Ws[k * 16];
#pragma unroll
            for (int f4 = 0; f4 < 4; ++f4) {
                float4 wv = wr[f4];
                acc[f4 * 4 + 0] = fmaf(xc[kk], wv.x, acc[f4 * 4 + 0]);
                acc[f4 * 4 + 1] = fmaf(xc[kk], wv.y, acc[f4 * 4 + 1]);
                acc[f4 * 4 + 2] = fmaf(xc[kk], wv.z, acc[f4 * 4 + 2]);
                acc[f4 * 4 + 3] = fmaf(xc[kk], wv.w, acc[f4 * 4 + 3]);
            }
        }
    }
    float dd = dinv[node];
    float4* ho = (float4*)(h1s + (size_t)node * 16);
#pragma unroll
    for (int f4 = 0; f4 < 4; ++f4)
        ho[f4] = make_float4(acc[f4 * 4 + 0] * dd, acc[f4 * 4 + 1] * dd,
                             acc[f4 * 4 + 2] * dd, acc[f4 * 4 + 3] * dd);
}

// ================= bucket aggregation layer 1 + self + bias + relu =================
// acc[dl][f] += h1s[src][f]; out = relu((acc + h1s[node]) * dinv[node] + b1) * dinv[node]
// (output pre-scaled for layer 2: h1s2 = relu(.)*dinv)

__global__ __launch_bounds__(256) void k_agg1(const int* __restrict__ csr,
                                              const int* __restrict__ bases,
                                              const float* __restrict__ dinv,
                                              const float* __restrict__ h1s,
                                              const float* __restrict__ b1,
                                              float* __restrict__ h1s2, int n) {
    __shared__ float acc[RB * 17];
    for (int i = threadIdx.x; i < RB * 17; i += 256) acc[i] = 0.f;
    __syncthreads();
    int bu = blockIdx.x;
    int e0 = bases[bu], e1 = bases[bu + 1];
    const float4* h4 = (const float4*)h1s;
    for (int i = e0 + threadIdx.x; i < e1; i += 256) {
        int p = csr[i];
        int s = p & 0xFFFFF;
        int dl = p >> 20;
        float4 a0 = h4[s * 4 + 0], a1 = h4[s * 4 + 1], a2 = h4[s * 4 + 2], a3 = h4[s * 4 + 3];
        float r[16];
        *(float4*)&r[0] = a0; *(float4*)&r[4] = a1;
        *(float4*)&r[8] = a2; *(float4*)&r[12] = a3;
        float* A = &acc[dl * 17];
#pragma unroll
        for (int f = 0; f < 16; ++f) atomicAdd(A + f, r[f]);
    }
    __syncthreads();
    int node0 = bu << 7;
    for (int idx = threadIdx.x; idx < RB * 16; idx += 256) {
        int dl = idx >> 4, f = idx & 15;
        int node = node0 + dl;
        if (node < n) {
            float dd = dinv[node];
            float v = (acc[dl * 17 + f] + h1s[node * 16 + f]) * dd + b1[f];
            h1s2[node * 16 + f] = fmaxf(v, 0.f) * dd;
        }
    }
}

// ================= bucket aggregation layer 2, fused W2+bias+log_softmax =============
// g = (acc + h1s2[node]) * dinv[node]; out = log_softmax(g @ W2 + b2)

__global__ __launch_bounds__(256) void k_agg2(const int* __restrict__ csr,
                                              const int* __restrict__ bases,
                                              const float* __restrict__ dinv,
                                              const float* __restrict__ h1s2,
                                              const float* __restrict__ W2,
                                              const float* __restrict__ b2,
                                              float* __restrict__ out, int n) {
    __shared__ float acc[RB * 17];
    __shared__ float Ws[F_HID * N_CLS];
    __shared__ float bs[N_CLS];
    if (threadIdx.x < F_HID * N_CLS) Ws[threadIdx.x] = W2[threadIdx.x];
    if (threadIdx.x < N_CLS) bs[threadIdx.x] = b2[threadIdx.x];
    for (int i = threadIdx.x; i < RB * 17; i += 256) acc[i] = 0.f;
    __syncthreads();
    int bu = blockIdx.x;
    int e0 = bases[bu], e1 = bases[bu + 1];
    const float4* h4 = (const float4*)h1s2;
    for (int i = e0 + threadIdx.x; i < e1; i += 256) {
        int p = csr[i];
        int s = p & 0xFFFFF;
        int dl = p >> 20;
        float4 a0 = h4[s * 4 + 0], a1 = h4[s * 4 + 1], a2 = h4[s * 4 + 2], a3 = h4[s * 4 + 3];
        float r[16];
        *(float4*)&r[0] = a0; *(float4*)&r[4] = a1;
        *(float4*)&r[8] = a2; *(float4*)&r[12] = a3;
        float* A = &acc[dl * 17];
#pragma unroll
        for (int f = 0; f < 16; ++f) atomicAdd(A + f, r[f]);
    }
    __syncthreads();
    if (threadIdx.x < RB) {
        int node = (bu << 7) + threadIdx.x;
        if (node < n) {
            float dd = dinv[node];
            const float4* hr4 = (const float4*)(h1s2 + node * 16);
            float4 r0 = hr4[0], r1 = hr4[1], r2 = hr4[2], r3 = hr4[3];
            float hr[16];
            *(float4*)&hr[0] = r0; *(float4*)&hr[4] = r1;
            *(float4*)&hr[8] = r2; *(float4*)&hr[12] = r3;
            float g[F_HID];
#pragma unroll
            for (int k = 0; k < F_HID; ++k)
                g[k] = (acc[threadIdx.x * 17 + k] + hr[k]) * dd;
            float logit[N_CLS];
#pragma unroll
            for (int c = 0; c < N_CLS; ++c) logit[c] = bs[c];
#pragma unroll
            for (int k = 0; k < F_HID; ++k)
#pragma unroll
                for (int c = 0; c < N_CLS; ++c)
                    logit[c] = fmaf(g[k], Ws[k * N_CLS + c], logit[c]);
            float m = -1e30f;
#pragma unroll
            for (int c = 0; c < N_CLS; ++c) m = fmaxf(m, logit[c]);
            float sum = 0.f;
#pragma unroll
            for (int c = 0; c < N_CLS; ++c) sum += expf(logit[c] - m);
            float lse = logf(sum);
#pragma unroll
            for (int c = 0; c < N_CLS; ++c) out[node * N_CLS + c] = logit[c] - m - lse;
        }
    }
}

extern "C" void kernel_launch(void* const* d_in, const int* in_sizes, int n_in,
                              void* d_out, int out_size, void* d_ws, size_t ws_size,
                              hipStream_t stream) {
    const float* x  = (const float*)d_in[0];
    const int*   ei = (const int*)d_in[1];
    const float* W1 = (const float*)d_in[2];
    const float* b1 = (const float*)d_in[3];
    const float* W2 = (const float*)d_in[4];
    const float* b2 = (const float*)d_in[5];
    float* out = (float*)d_out;

    const int n  = in_sizes[0] / F_IN;   // 100000
    const int ne = in_sizes[1] / 2;      // 6400000
    const int* src = ei;
    const int* dst = ei + ne;

    const int nbuk = (n + RB - 1) >> 7;          // 782
    const int nt   = (ne + TILE - 1) / TILE;     // 391

    char* ws = (char*)d_ws;
    size_t off = 0;
    auto carve = [&](size_t bytes) -> void* {
        void* p = ws + off;
        off += (bytes + 255) & ~(size_t)255;
        return p;
    };
    int*   th     = (int*)  carve((size_t)nt * nbuk * 4);   // 1.22 MB
    int*   totals = (int*)  carve((size_t)nbuk * 4);
    int*   bases  = (int*)  carve((size_t)(nbuk + 1) * 4);
    float* dinv   = (float*)carve((size_t)n * 4);
    int*   csr    = (int*)  carve((size_t)ne * 4);          // 25.6 MB
    float* h1s    = (float*)carve((size_t)n * F_HID * 4);   // 6.4 MB
    float* h1s2   = (float*)carve((size_t)n * F_HID * 4);   // 6.4 MB
    (void)ws_size;

    k_tilehist<<<nt, 256, 0, stream>>>(dst, th, ne, nbuk);
    k_colscan<<<nbuk, 256, 0, stream>>>(th, totals, nt, nbuk);
    k_bscan<<<1, 1024, 0, stream>>>(totals, bases, nbuk);
    k_tilescatter<<<nt, 256, 0, stream>>>(src, dst, th, bases, csr, ne, nbuk);
    k_dinvcsr<<<nbuk, 256, 0, stream>>>(csr, bases, dinv, n);

    k_gemm1<<<(n + 255) / 256, 256, 0, stream>>>(x, W1, dinv, h1s, n);
    k_agg1<<<nbuk, 256, 0, stream>>>(csr, bases, dinv, h1s, b1, h1s2, n);
    k_agg2<<<nbuk, 256, 0, stream>>>(csr, bases, dinv, h1s2, W2, b2, out, n);
}

// Round 6
// 529.938 us; speedup vs baseline: 3.0944x; 3.0944x over previous
//
#include <hip/hip_runtime.h>

#define F_IN 128
#define F_HID 16
#define N_CLS 10
#define TILE 16384          // edges per binning tile
#define RB 128              // nodes per bucket (dst >> 7)
#define MAXBUK 1024
#define CAP 12800           // max edges per bucket for LDS sort (mean 8184, sigma ~90)

// ================= binning: per-tile bucket histogram =================

__global__ __launch_bounds__(256) void k_tilehist(const int* __restrict__ dst,
                                                  int* __restrict__ th, int ne, int nbuk) {
    __shared__ int h[MAXBUK];
    int t = blockIdx.x;
    for (int i = threadIdx.x; i < nbuk; i += 256) h[i] = 0;
    __syncthreads();
    int e0 = t * TILE, e1 = min(e0 + TILE, ne);
    for (int i = e0 + threadIdx.x; i < e1; i += 256)
        atomicAdd(&h[dst[i] >> 7], 1);
    __syncthreads();
    for (int i = threadIdx.x; i < nbuk; i += 256) th[t * nbuk + i] = h[i];
}

// ================= binning: per-bucket scan across tiles =================

__global__ __launch_bounds__(256) void k_colscan(int* __restrict__ th,
                                                 int* __restrict__ totals, int nt, int nbuk) {
    int b = blockIdx.x;
    __shared__ int sm[256];
    __shared__ int s_run;
    if (threadIdx.x == 0) s_run = 0;
    __syncthreads();
    for (int t0 = 0; t0 < nt; t0 += 256) {
        int t = t0 + threadIdx.x;
        int v = (t < nt) ? th[t * nbuk + b] : 0;
        sm[threadIdx.x] = v;
        __syncthreads();
        int acc = v;
        for (int d = 1; d < 256; d <<= 1) {
            int add = (threadIdx.x >= d) ? sm[threadIdx.x - d] : 0;
            __syncthreads();
            acc += add;
            sm[threadIdx.x] = acc;
            __syncthreads();
        }
        int run = s_run;
        if (t < nt) th[t * nbuk + b] = run + acc - v;   // exclusive within bucket
        __syncthreads();
        if (threadIdx.x == 255) s_run = run + acc;
        __syncthreads();
    }
    if (threadIdx.x == 0) totals[b] = s_run;
}

// single-block exclusive scan of totals -> bases[0..nbuk], bases[nbuk]=ne

__global__ __launch_bounds__(1024) void k_bscan(const int* __restrict__ totals,
                                                int* __restrict__ bases, int nb) {
    __shared__ int sm[1024];
    int t = threadIdx.x;
    int v = (t < nb) ? totals[t] : 0;
    sm[t] = v;
    __syncthreads();
    int acc = v;
    for (int d = 1; d < 1024; d <<= 1) {
        int add = (t >= d) ? sm[t - d] : 0;
        __syncthreads();
        acc += add;
        sm[t] = acc;
        __syncthreads();
    }
    if (t < nb) bases[t] = acc - v;
    if (t == nb - 1) bases[nb] = acc;
}

// ================= binning: scatter into bucket-grouped array =================
// pack = (dst_local << 20) | src   (src < 2^20, dst_local < 128)

__global__ __launch_bounds__(256) void k_tilescatter(const int* __restrict__ src,
                                                     const int* __restrict__ dst,
                                                     const int* __restrict__ th,
                                                     const int* __restrict__ bases,
                                                     int* __restrict__ csr, int ne, int nbuk) {
    __shared__ int cur[MAXBUK];
    int t = blockIdx.x;
    for (int i = threadIdx.x; i < nbuk; i += 256)
        cur[i] = bases[i] + th[t * nbuk + i];
    __syncthreads();
    int e0 = t * TILE, e1 = min(e0 + TILE, ne);
    for (int i = e0 + threadIdx.x; i < e1; i += 256) {
        int d = dst[i], s = src[i];
        int b = d >> 7;
        int p = atomicAdd(&cur[b], 1);
        csr[p] = ((d & 127) << 20) | s;
    }
}

// ================= per-bucket node sort (in place) + dinv + offs =================
// Pass A: LDS histogram of dst_local (= per-node in-degree) -> dinv, offs.
// Pass B: re-read bucket, scatter src into LDS by node, write back coalesced.

__global__ __launch_bounds__(256) void k_bsort(int* __restrict__ csr,
                                               const int* __restrict__ bases,
                                               float* __restrict__ dinv,
                                               int* __restrict__ offs,
                                               int n, int ne) {
    __shared__ int s_src[CAP];   // 51.2 KB
    __shared__ int h[RB];
    __shared__ int sc[RB];
    __shared__ int cur[RB];
    int bu = blockIdx.x;
    int e0 = bases[bu], e1 = bases[bu + 1];
    int cnt = e1 - e0;
    if (threadIdx.x < RB) h[threadIdx.x] = 0;
    __syncthreads();
    for (int i = e0 + threadIdx.x; i < e1; i += 256)
        atomicAdd(&h[csr[i] >> 20], 1);
    __syncthreads();
    if (threadIdx.x < RB) sc[threadIdx.x] = h[threadIdx.x];
    __syncthreads();
    for (int d = 1; d < RB; d <<= 1) {
        int v = 0;
        if (threadIdx.x < RB && threadIdx.x >= d) v = sc[threadIdx.x - d];
        __syncthreads();
        if (threadIdx.x < RB) sc[threadIdx.x] += v;
        __syncthreads();
    }
    if (threadIdx.x < RB) {
        int excl = sc[threadIdx.x] - h[threadIdx.x];
        cur[threadIdx.x] = excl;
        int node = (bu << 7) + threadIdx.x;
        if (node < n) {
            dinv[node] = rsqrtf((float)(h[threadIdx.x] + 1));  // +1 self-loop
            offs[node] = e0 + excl;
        }
    }
    if (bu == 0 && threadIdx.x == 0) offs[n] = ne;
    __syncthreads();
    for (int i = e0 + threadIdx.x; i < e1; i += 256) {
        int p = csr[i];
        int pos = atomicAdd(&cur[p >> 20], 1);
        s_src[pos] = p & 0xFFFFF;
    }
    __syncthreads();
    for (int j = threadIdx.x; j < cnt; j += 256)
        csr[e0 + j] = s_src[j];
}

// ================= layer 1 linear (pre-scaled): h1s = (x @ W1) * dinv =================

__global__ __launch_bounds__(256) void k_gemm1(const float* __restrict__ x,
                                               const float* __restrict__ W1,
                                               const float* __restrict__ dinv,
                                               float* __restrict__ h1s, int n) {
    __shared__ float Ws[F_IN * F_HID];  // [k][f], 8 KB
    for (int i = threadIdx.x; i < F_IN * F_HID; i += 256) Ws[i] = W1[i];
    __syncthreads();
    int node = blockIdx.x * 256 + threadIdx.x;
    if (node >= n) return;
    const float4* xr = (const float4*)(x + (size_t)node * F_IN);
    float acc[16];
#pragma unroll
    for (int f = 0; f < 16; ++f) acc[f] = 0.f;
#pragma unroll 8
    for (int k4 = 0; k4 < 32; ++k4) {
        float4 xv = xr[k4];
        float xc[4] = {xv.x, xv.y, xv.z, xv.w};
#pragma unroll
        for (int kk = 0; kk < 4; ++kk) {
            int k = k4 * 4 + kk;
            const float4* wr = (const float4*)&Ws[k * 16];
#pragma unroll
            for (int f4 = 0; f4 < 4; ++f4) {
                float4 wv = wr[f4];
                acc[f4 * 4 + 0] = fmaf(xc[kk], wv.x, acc[f4 * 4 + 0]);
                acc[f4 * 4 + 1] = fmaf(xc[kk], wv.y, acc[f4 * 4 + 1]);
                acc[f4 * 4 + 2] = fmaf(xc[kk], wv.z, acc[f4 * 4 + 2]);
                acc[f4 * 4 + 3] = fmaf(xc[kk], wv.w, acc[f4 * 4 + 3]);
            }
        }
    }
    float dd = dinv[node];
    float4* ho = (float4*)(h1s + (size_t)node * 16);
#pragma unroll
    for (int f4 = 0; f4 < 4; ++f4)
        ho[f4] = make_float4(acc[f4 * 4 + 0] * dd, acc[f4 * 4 + 1] * dd,
                             acc[f4 * 4 + 2] * dd, acc[f4 * 4 + 3] * dd);
}

// ================= aggregation layer 1 (wave per node, register acc) =================
// h1s2 = relu((sum_{s in N(d)} h1s[s] + h1s[d]) * dinv[d] + b1) * dinv[d]

__global__ __launch_bounds__(256) void k_agg1(const int* __restrict__ csr,
                                              const int* __restrict__ offs,
                                              const float* __restrict__ dinv,
                                              const float* __restrict__ h1s,
                                              const float* __restrict__ b1,
                                              float* __restrict__ h1s2, int n) {
    int node = blockIdx.x * 4 + (threadIdx.x >> 6);
    if (node >= n) return;
    int lane = threadIdx.x & 63;
    int slot = lane >> 4, f = lane & 15;
    int off = offs[node], end = offs[node + 1];
    float acc = 0.f;
    int i = off + slot;
    for (; i + 4 < end; i += 8) {         // 2 edges per slot in flight
        int sA = csr[i], sB = csr[i + 4];
        float a = h1s[sA * 16 + f];
        float b = h1s[sB * 16 + f];
        acc += a + b;
    }
    if (i < end) acc += h1s[csr[i] * 16 + f];
    acc += __shfl_xor(acc, 16);
    acc += __shfl_xor(acc, 32);
    if (slot == 0) {
        float dd = dinv[node];
        float v = (acc + h1s[node * 16 + f]) * dd + b1[f];
        h1s2[node * 16 + f] = fmaxf(v, 0.f) * dd;
    }
}

// ================= aggregation layer 2 + fused W2 + bias + log_softmax =================

__global__ __launch_bounds__(256) void k_agg2(const int* __restrict__ csr,
                                              const int* __restrict__ offs,
                                              const float* __restrict__ dinv,
                                              const float* __restrict__ h1s2,
                                              const float* __restrict__ W2,
                                              const float* __restrict__ b2,
                                              float* __restrict__ out, int n) {
    __shared__ float Ws[F_HID * N_CLS];
    __shared__ float bs[N_CLS];
    if (threadIdx.x < F_HID * N_CLS) Ws[threadIdx.x] = W2[threadIdx.x];
    if (threadIdx.x < N_CLS) bs[threadIdx.x] = b2[threadIdx.x];
    __syncthreads();
    int node = blockIdx.x * 4 + (threadIdx.x >> 6);
    if (node >= n) return;
    int lane = threadIdx.x & 63;
    int slot = lane >> 4, f = lane & 15;
    int off = offs[node], end = offs[node + 1];
    float acc = 0.f;
    int i = off + slot;
    for (; i + 4 < end; i += 8) {
        int sA = csr[i], sB = csr[i + 4];
        float a = h1s2[sA * 16 + f];
        float b = h1s2[sB * 16 + f];
        acc += a + b;
    }
    if (i < end) acc += h1s2[csr[i] * 16 + f];
    acc += __shfl_xor(acc, 16);
    acc += __shfl_xor(acc, 32);
    // every lane holds g for feature f = lane & 15
    float dd = dinv[node];
    float g = (acc + h1s2[node * 16 + f]) * dd;
    float lo[N_CLS];
#pragma unroll
    for (int c = 0; c < N_CLS; ++c) lo[c] = g * Ws[f * N_CLS + c] + bs[c] * (1.f / 16.f);
#pragma unroll
    for (int d = 1; d < 16; d <<= 1)
#pragma unroll
        for (int c = 0; c < N_CLS; ++c) lo[c] += __shfl_xor(lo[c], d);
    // all lanes now hold the full logits
    if (lane < N_CLS) {
        float m = lo[0];
#pragma unroll
        for (int c = 1; c < N_CLS; ++c) m = fmaxf(m, lo[c]);
        float sum = 0.f;
#pragma unroll
        for (int c = 0; c < N_CLS; ++c) sum += expf(lo[c] - m);
        float lse = m + logf(sum);
        out[node * N_CLS + lane] = lo[lane] - lse;
    }
}

extern "C" void kernel_launch(void* const* d_in, const int* in_sizes, int n_in,
                              void* d_out, int out_size, void* d_ws, size_t ws_size,
                              hipStream_t stream) {
    const float* x  = (const float*)d_in[0];
    const int*   ei = (const int*)d_in[1];
    const float* W1 = (const float*)d_in[2];
    const float* b1 = (const float*)d_in[3];
    const float* W2 = (const float*)d_in[4];
    const float* b2 = (const float*)d_in[5];
    float* out = (float*)d_out;

    const int n  = in_sizes[0] / F_IN;   // 100000
    const int ne = in_sizes[1] / 2;      // 6400000
    const int* src = ei;
    const int* dst = ei + ne;

    const int nbuk = (n + RB - 1) >> 7;          // 782
    const int nt   = (ne + TILE - 1) / TILE;     // 391

    char* ws = (char*)d_ws;
    size_t off = 0;
    auto carve = [&](size_t bytes) -> void* {
        void* p = ws + off;
        off += (bytes + 255) & ~(size_t)255;
        return p;
    };
    int*   th     = (int*)  carve((size_t)nt * nbuk * 4);   // 1.22 MB
    int*   totals = (int*)  carve((size_t)nbuk * 4);
    int*   bases  = (int*)  carve((size_t)(nbuk + 1) * 4);
    float* dinv   = (float*)carve((size_t)n * 4);
    int*   csr    = (int*)  carve((size_t)ne * 4);          // 25.6 MB
    int*   offsA  = (int*)  carve((size_t)(n + 1) * 4);
    float* h1s    = (float*)carve((size_t)n * F_HID * 4);   // 6.4 MB
    float* h1s2   = (float*)carve((size_t)n * F_HID * 4);   // 6.4 MB
    (void)ws_size;

    k_tilehist<<<nt, 256, 0, stream>>>(dst, th, ne, nbuk);
    k_colscan<<<nbuk, 256, 0, stream>>>(th, totals, nt, nbuk);
    k_bscan<<<1, 1024, 0, stream>>>(totals, bases, nbuk);
    k_tilescatter<<<nt, 256, 0, stream>>>(src, dst, th, bases, csr, ne, nbuk);
    k_bsort<<<nbuk, 256, 0, stream>>>(csr, bases, dinv, offsA, n, ne);

    k_gemm1<<<(n + 255) / 256, 256, 0, stream>>>(x, W1, dinv, h1s, n);
    k_agg1<<<(n + 3) / 4, 256, 0, stream>>>(csr, offsA, dinv, h1s, b1, h1s2, n);
    k_agg2<<<(n + 3) / 4, 256, 0, stream>>>(csr, offsA, dinv, h1s2, W2, b2, out, n);
}

// Round 7
// 469.833 us; speedup vs baseline: 3.4902x; 1.1279x over previous
//
#include <hip/hip_runtime.h>

#define F_IN 128
#define F_HID 16
#define N_CLS 10
#define TILE 16384          // edges per level-1 tile
#define SH_C 10             // coarse bucket = dst >> 10 (1024 nodes)
#define RB 128              // fine bucket = 128 nodes (dst >> 7)
#define CAP 12800           // max edges per fine bucket for LDS sort (mean ~8.2k, sigma ~90)

// ====== hist: per-tile coarse histogram + global fine totals ======

__global__ __launch_bounds__(256) void k_hist2(const int* __restrict__ dst,
                                               int* __restrict__ th,      // [nt][nbc]
                                               int* __restrict__ ftot,    // [nfb] (pre-zeroed)
                                               int ne, int nbc, int nfb) {
    __shared__ int h[1024];
    int t = blockIdx.x;
    for (int i = threadIdx.x; i < nfb; i += 256) h[i] = 0;
    __syncthreads();
    int e0 = t * TILE, e1 = min(e0 + TILE, ne);
    for (int i = e0 + threadIdx.x; i < e1; i += 256)
        atomicAdd(&h[dst[i] >> 7], 1);
    __syncthreads();
    if (threadIdx.x < nbc) {
        int s = 0;
#pragma unroll
        for (int f = 0; f < 8; ++f) s += h[threadIdx.x * 8 + f];
        th[t * nbc + threadIdx.x] = s;
    }
    for (int i = threadIdx.x; i < nfb; i += 256)
        if (h[i]) atomicAdd(&ftot[i], h[i]);
}

// ====== per-coarse-bucket scan across tiles (prefix within bucket) ======

__global__ __launch_bounds__(256) void k_colscan(int* __restrict__ th, int nt, int nbc) {
    int b = blockIdx.x;
    __shared__ int sm[256];
    __shared__ int s_run;
    if (threadIdx.x == 0) s_run = 0;
    __syncthreads();
    for (int t0 = 0; t0 < nt; t0 += 256) {
        int t = t0 + threadIdx.x;
        int v = (t < nt) ? th[t * nbc + b] : 0;
        sm[threadIdx.x] = v;
        __syncthreads();
        int acc = v;
        for (int d = 1; d < 256; d <<= 1) {
            int add = (threadIdx.x >= d) ? sm[threadIdx.x - d] : 0;
            __syncthreads();
            acc += add;
            sm[threadIdx.x] = acc;
            __syncthreads();
        }
        int run = s_run;
        if (t < nt) th[t * nbc + b] = run + acc - v;   // exclusive within bucket
        __syncthreads();
        if (threadIdx.x == 255) s_run = run + acc;
        __syncthreads();
    }
}

// ====== exclusive scan of fine totals -> fbases[0..nfb], fbases[nfb]=ne ======

__global__ __launch_bounds__(1024) void k_bscan(const int* __restrict__ totals,
                                                int* __restrict__ bases, int nb) {
    __shared__ int sm[1024];
    int t = threadIdx.x;
    int v = (t < nb) ? totals[t] : 0;
    sm[t] = v;
    __syncthreads();
    int acc = v;
    for (int d = 1; d < 1024; d <<= 1) {
        int add = (t >= d) ? sm[t - d] : 0;
        __syncthreads();
        acc += add;
        sm[t] = acc;
        __syncthreads();
    }
    if (t < nb) bases[t] = acc - v;
    if (t == nb - 1) bases[nb] = acc;
}

// ====== level-1 scatter into coarse-bucket-grouped array ======
// pack = (dst_low10 << 20) | src   (src < 2^20)

__global__ __launch_bounds__(256) void k_tilescatter(const int* __restrict__ src,
                                                     const int* __restrict__ dst,
                                                     const int* __restrict__ th,
                                                     const int* __restrict__ fbases,
                                                     int* __restrict__ csr, int ne, int nbc) {
    __shared__ int cur[128];
    int t = blockIdx.x;
    for (int i = threadIdx.x; i < nbc; i += 256)
        cur[i] = fbases[i * 8] + th[t * nbc + i];
    __syncthreads();
    int e0 = t * TILE, e1 = min(e0 + TILE, ne);
    for (int i = e0 + threadIdx.x; i < e1; i += 256) {
        int d = dst[i], s = src[i];
        int b = d >> SH_C;
        int p = atomicAdd(&cur[b], 1);
        csr[p] = ((d & 1023) << 20) | s;
    }
}

// ====== level-2 split: coarse bucket -> 8 fine buckets (8 open cursors) ======

__global__ __launch_bounds__(1024) void k_split(const int* __restrict__ csr,
                                                const int* __restrict__ fbases,
                                                int* __restrict__ csr2, int nbc) {
    __shared__ int cur8[8];
    int bu = blockIdx.x;
    if (threadIdx.x < 8) cur8[threadIdx.x] = fbases[bu * 8 + threadIdx.x];
    __syncthreads();
    int e0 = fbases[bu * 8], e1 = fbases[bu * 8 + 8];
    for (int i = e0 + (int)threadIdx.x; i < e1; i += 1024) {
        int p = csr[i];
        int fid = (p >> 27) & 7;
        int pos = atomicAdd(&cur8[fid], 1);
        csr2[pos] = p;
    }
}

// ====== per-fine-bucket node sort (in place) + dinv + offs ======

__global__ __launch_bounds__(256) void k_bsort(int* __restrict__ csr,
                                               const int* __restrict__ fbases,
                                               float* __restrict__ dinv,
                                               int* __restrict__ offs,
                                               int n, int ne) {
    __shared__ int s_src[CAP];   // 51.2 KB
    __shared__ int h[RB];
    __shared__ int sc[RB];
    __shared__ int cur[RB];
    int bu = blockIdx.x;
    int e0 = fbases[bu], e1 = fbases[bu + 1];
    int cnt = e1 - e0;
    if (threadIdx.x < RB) h[threadIdx.x] = 0;
    __syncthreads();
    for (int i = e0 + threadIdx.x; i < e1; i += 256)
        atomicAdd(&h[(csr[i] >> 20) & 127], 1);
    __syncthreads();
    if (threadIdx.x < RB) sc[threadIdx.x] = h[threadIdx.x];
    __syncthreads();
    for (int d = 1; d < RB; d <<= 1) {
        int v = 0;
        if (threadIdx.x < RB && threadIdx.x >= d) v = sc[threadIdx.x - d];
        __syncthreads();
        if (threadIdx.x < RB) sc[threadIdx.x] += v;
        __syncthreads();
    }
    if (threadIdx.x < RB) {
        int excl = sc[threadIdx.x] - h[threadIdx.x];
        cur[threadIdx.x] = excl;
        int node = (bu << 7) + threadIdx.x;
        if (node < n) {
            dinv[node] = rsqrtf((float)(h[threadIdx.x] + 1));  // +1 self-loop
            offs[node] = e0 + excl;
        }
    }
    if (bu == 0 && threadIdx.x == 0) offs[n] = ne;
    __syncthreads();
    for (int i = e0 + threadIdx.x; i < e1; i += 256) {
        int p = csr[i];
        int pos = atomicAdd(&cur[(p >> 20) & 127], 1);
        s_src[pos] = p & 0xFFFFF;
    }
    __syncthreads();
    for (int j = threadIdx.x; j < cnt; j += 256)
        csr[e0 + j] = s_src[j];
}

// ====== layer 1 linear (pre-scaled): h1s = (x @ W1) * dinv ======
// block = 16 nodes x 16 feats; x rows staged via coalesced loads.

__global__ __launch_bounds__(256) void k_gemm1(const float* __restrict__ x,
                                               const float* __restrict__ W1,
                                               const float* __restrict__ dinv,
                                               float* __restrict__ h1s, int n) {
    __shared__ float Ws[F_IN * F_HID];   // 8 KB
    __shared__ float xs[16][F_IN + 1];   // 8.3 KB, padded
    for (int i = threadIdx.x; i < F_IN * F_HID; i += 256) Ws[i] = W1[i];
    int node0 = blockIdx.x * 16;
    for (int i = threadIdx.x; i < 16 * F_IN; i += 256) {
        int r = i >> 7, c = i & 127;
        int node = node0 + r;
        xs[r][c] = (node < n) ? x[(size_t)node * F_IN + c] : 0.f;
    }
    __syncthreads();
    int r = threadIdx.x >> 4, f = threadIdx.x & 15;
    int node = node0 + r;
    if (node < n) {
        float acc = 0.f;
#pragma unroll
        for (int k = 0; k < F_IN; ++k) acc = fmaf(xs[r][k], Ws[k * F_HID + f], acc);
        h1s[node * F_HID + f] = acc * dinv[node];
    }
}

// ====== aggregation layer 1 (wave per node, register acc, 4-deep) ======

__global__ __launch_bounds__(256) void k_agg1(const int* __restrict__ csr,
                                              const int* __restrict__ offs,
                                              const float* __restrict__ dinv,
                                              const float* __restrict__ h1s,
                                              const float* __restrict__ b1,
                                              float* __restrict__ h1s2, int n) {
    int node = blockIdx.x * 4 + (threadIdx.x >> 6);
    if (node >= n) return;
    int lane = threadIdx.x & 63;
    int slot = lane >> 4, f = lane & 15;
    int off = offs[node], end = offs[node + 1];
    float acc = 0.f;
    int i = off + slot;
    for (; i + 12 < end; i += 16) {
        int s0 = csr[i], s1 = csr[i + 4], s2 = csr[i + 8], s3 = csr[i + 12];
        float a = h1s[s0 * 16 + f];
        float b = h1s[s1 * 16 + f];
        float c = h1s[s2 * 16 + f];
        float d = h1s[s3 * 16 + f];
        acc += (a + b) + (c + d);
    }
    for (; i < end; i += 4) acc += h1s[csr[i] * 16 + f];
    acc += __shfl_xor(acc, 16);
    acc += __shfl_xor(acc, 32);
    if (slot == 0) {
        float dd = dinv[node];
        float v = (acc + h1s[node * 16 + f]) * dd + b1[f];
        h1s2[node * 16 + f] = fmaxf(v, 0.f) * dd;
    }
}

// ====== aggregation layer 2 + fused W2 + bias + log_softmax ======

__global__ __launch_bounds__(256) void k_agg2(const int* __restrict__ csr,
                                              const int* __restrict__ offs,
                                              const float* __restrict__ dinv,
                                              const float* __restrict__ h1s2,
                                              const float* __restrict__ W2,
                                              const float* __restrict__ b2,
                                              float* __restrict__ out, int n) {
    __shared__ float Ws[F_HID * N_CLS];
    __shared__ float bs[N_CLS];
    if (threadIdx.x < F_HID * N_CLS) Ws[threadIdx.x] = W2[threadIdx.x];
    if (threadIdx.x < N_CLS) bs[threadIdx.x] = b2[threadIdx.x];
    __syncthreads();
    int node = blockIdx.x * 4 + (threadIdx.x >> 6);
    if (node >= n) return;
    int lane = threadIdx.x & 63;
    int slot = lane >> 4, f = lane & 15;
    int off = offs[node], end = offs[node + 1];
    float acc = 0.f;
    int i = off + slot;
    for (; i + 12 < end; i += 16) {
        int s0 = csr[i], s1 = csr[i + 4], s2 = csr[i + 8], s3 = csr[i + 12];
        float a = h1s2[s0 * 16 + f];
        float b = h1s2[s1 * 16 + f];
        float c = h1s2[s2 * 16 + f];
        float d = h1s2[s3 * 16 + f];
        acc += (a + b) + (c + d);
    }
    for (; i < end; i += 4) acc += h1s2[csr[i] * 16 + f];
    acc += __shfl_xor(acc, 16);
    acc += __shfl_xor(acc, 32);
    // every lane holds g for feature f = lane & 15
    float dd = dinv[node];
    float g = (acc + h1s2[node * 16 + f]) * dd;
    float lo[N_CLS];
#pragma unroll
    for (int c = 0; c < N_CLS; ++c) lo[c] = g * Ws[f * N_CLS + c] + bs[c] * (1.f / 16.f);
#pragma unroll
    for (int d = 1; d < 16; d <<= 1)
#pragma unroll
        for (int c = 0; c < N_CLS; ++c) lo[c] += __shfl_xor(lo[c], d);
    if (lane < N_CLS) {
        float m = lo[0];
#pragma unroll
        for (int c = 1; c < N_CLS; ++c) m = fmaxf(m, lo[c]);
        float sum = 0.f;
#pragma unroll
        for (int c = 0; c < N_CLS; ++c) sum += expf(lo[c] - m);
        float lse = m + logf(sum);
        out[node * N_CLS + lane] = lo[lane] - lse;
    }
}

extern "C" void kernel_launch(void* const* d_in, const int* in_sizes, int n_in,
                              void* d_out, int out_size, void* d_ws, size_t ws_size,
                              hipStream_t stream) {
    const float* x  = (const float*)d_in[0];
    const int*   ei = (const int*)d_in[1];
    const float* W1 = (const float*)d_in[2];
    const float* b1 = (const float*)d_in[3];
    const float* W2 = (const float*)d_in[4];
    const float* b2 = (const float*)d_in[5];
    float* out = (float*)d_out;

    const int n  = in_sizes[0] / F_IN;   // 100000
    const int ne = in_sizes[1] / 2;      // 6400000
    const int* src = ei;
    const int* dst = ei + ne;

    const int nbc = (n + (1 << SH_C) - 1) >> SH_C;   // 98 coarse buckets
    const int nfb = nbc * 8;                          // 784 fine buckets
    const int nt  = (ne + TILE - 1) / TILE;           // 391 tiles

    char* ws = (char*)d_ws;
    size_t off = 0;
    auto carve = [&](size_t bytes) -> void* {
        void* p = ws + off;
        off += (bytes + 255) & ~(size_t)255;
        return p;
    };
    int*   th     = (int*)  carve((size_t)nt * nbc * 4);    // 153 KB
    int*   ftot   = (int*)  carve((size_t)nfb * 4);
    int*   fbases = (int*)  carve((size_t)(nfb + 1) * 4);
    float* dinv   = (float*)carve((size_t)n * 4);
    int*   csr    = (int*)  carve((size_t)ne * 4);          // 25.6 MB
    int*   csr2   = (int*)  carve((size_t)ne * 4);          // 25.6 MB
    int*   offsA  = (int*)  carve((size_t)(n + 1) * 4);
    float* h1s    = (float*)carve((size_t)n * F_HID * 4);   // 6.4 MB
    float* h1s2   = (float*)carve((size_t)n * F_HID * 4);   // 6.4 MB
    (void)ws_size;

    hipMemsetAsync(ftot, 0, (size_t)nfb * 4, stream);

    k_hist2<<<nt, 256, 0, stream>>>(dst, th, ftot, ne, nbc, nfb);
    k_colscan<<<nbc, 256, 0, stream>>>(th, nt, nbc);
    k_bscan<<<1, 1024, 0, stream>>>(ftot, fbases, nfb);
    k_tilescatter<<<nt, 256, 0, stream>>>(src, dst, th, fbases, csr, ne, nbc);
    k_split<<<nbc, 1024, 0, stream>>>(csr, fbases, csr2, nbc);
    k_bsort<<<nfb, 256, 0, stream>>>(csr2, fbases, dinv, offsA, n, ne);

    k_gemm1<<<(n + 15) / 16, 256, 0, stream>>>(x, W1, dinv, h1s, n);
    k_agg1<<<(n + 3) / 4, 256, 0, stream>>>(csr2, offsA, dinv, h1s, b1, h1s2, n);
    k_agg2<<<(n + 3) / 4, 256, 0, stream>>>(csr2, offsA, dinv, h1s2, W2, b2, out, n);
}

// Round 8
// 420.448 us; speedup vs baseline: 3.9002x; 1.1175x over previous
//
#include <hip/hip_runtime.h>

#define F_IN 128
#define F_HID 16
#define N_CLS 10
#define TILE 16384          // edges per level-1 tile
#define SH_C 10             // coarse bucket = dst >> 10 (1024 nodes)
#define RB 128              // fine bucket = 128 nodes
#define CAP 12800           // max edges per fine bucket (mean ~8.2k, sigma ~90)

// bf16 helpers: pack two f32 -> one u32 (RNE), unpack lo/hi
__device__ __forceinline__ unsigned bpack2(float a, float b) {
    unsigned ua = __float_as_uint(a), ub = __float_as_uint(b);
    ua = (ua + 0x7fffu + ((ua >> 16) & 1u)) >> 16;
    ub = (ub + 0x7fffu + ((ub >> 16) & 1u)) >> 16;
    return ua | (ub << 16);
}
__device__ __forceinline__ float blo(unsigned w) { return __uint_as_float(w << 16); }
__device__ __forceinline__ float bhi(unsigned w) { return __uint_as_float(w & 0xffff0000u); }

// ====== hist: per-tile coarse histogram + global fine totals ======

__global__ __launch_bounds__(256) void k_hist2(const int* __restrict__ dst,
                                               int* __restrict__ th,      // [nt][nbc]
                                               int* __restrict__ ftot,    // [nfb] (pre-zeroed)
                                               int ne, int nbc, int nfb) {
    __shared__ int h[1024];
    int t = blockIdx.x;
    for (int i = threadIdx.x; i < nfb; i += 256) h[i] = 0;
    __syncthreads();
    int e0 = t * TILE, e1 = min(e0 + TILE, ne);
    for (int i = e0 + threadIdx.x; i < e1; i += 256)
        atomicAdd(&h[dst[i] >> 7], 1);
    __syncthreads();
    if (threadIdx.x < nbc) {
        int s = 0;
#pragma unroll
        for (int f = 0; f < 8; ++f) s += h[threadIdx.x * 8 + f];
        th[t * nbc + threadIdx.x] = s;
    }
    for (int i = threadIdx.x; i < nfb; i += 256)
        if (h[i]) atomicAdd(&ftot[i], h[i]);
}

// ====== per-coarse-bucket scan across tiles ======

__global__ __launch_bounds__(256) void k_colscan(int* __restrict__ th, int nt, int nbc) {
    int b = blockIdx.x;
    __shared__ int sm[256];
    __shared__ int s_run;
    if (threadIdx.x == 0) s_run = 0;
    __syncthreads();
    for (int t0 = 0; t0 < nt; t0 += 256) {
        int t = t0 + threadIdx.x;
        int v = (t < nt) ? th[t * nbc + b] : 0;
        sm[threadIdx.x] = v;
        __syncthreads();
        int acc = v;
        for (int d = 1; d < 256; d <<= 1) {
            int add = (threadIdx.x >= d) ? sm[threadIdx.x - d] : 0;
            __syncthreads();
            acc += add;
            sm[threadIdx.x] = acc;
            __syncthreads();
        }
        int run = s_run;
        if (t < nt) th[t * nbc + b] = run + acc - v;
        __syncthreads();
        if (threadIdx.x == 255) s_run = run + acc;
        __syncthreads();
    }
}

// ====== exclusive scan of fine totals -> fbases[0..nfb] ======

__global__ __launch_bounds__(1024) void k_bscan(const int* __restrict__ totals,
                                                int* __restrict__ bases, int nb) {
    __shared__ int sm[1024];
    int t = threadIdx.x;
    int v = (t < nb) ? totals[t] : 0;
    sm[t] = v;
    __syncthreads();
    int acc = v;
    for (int d = 1; d < 1024; d <<= 1) {
        int add = (t >= d) ? sm[t - d] : 0;
        __syncthreads();
        acc += add;
        sm[t] = acc;
        __syncthreads();
    }
    if (t < nb) bases[t] = acc - v;
    if (t == nb - 1) bases[nb] = acc;
}

// ====== level-1 scatter into coarse-bucket-grouped array ======

__global__ __launch_bounds__(256) void k_tilescatter(const int* __restrict__ src,
                                                     const int* __restrict__ dst,
                                                     const int* __restrict__ th,
                                                     const int* __restrict__ fbases,
                                                     int* __restrict__ csr, int ne, int nbc) {
    __shared__ int cur[128];
    int t = blockIdx.x;
    for (int i = threadIdx.x; i < nbc; i += 256)
        cur[i] = fbases[i * 8] + th[t * nbc + i];
    __syncthreads();
    int e0 = t * TILE, e1 = min(e0 + TILE, ne);
    for (int i = e0 + threadIdx.x; i < e1; i += 256) {
        int d = dst[i], s = src[i];
        int b = d >> SH_C;
        int p = atomicAdd(&cur[b], 1);
        csr[p] = ((d & 1023) << 20) | s;
    }
}

// ====== level-2 split: coarse bucket -> 8 fine buckets ======

__global__ __launch_bounds__(1024) void k_split(const int* __restrict__ csr,
                                                const int* __restrict__ fbases,
                                                int* __restrict__ csr2, int nbc) {
    __shared__ int cur8[8];
    int bu = blockIdx.x;
    if (threadIdx.x < 8) cur8[threadIdx.x] = fbases[bu * 8 + threadIdx.x];
    __syncthreads();
    int e0 = fbases[bu * 8], e1 = fbases[bu * 8 + 8];
    for (int i = e0 + (int)threadIdx.x; i < e1; i += 1024) {
        int p = csr[i];
        int fid = (p >> 27) & 7;
        int pos = atomicAdd(&cur8[fid], 1);
        csr2[pos] = p;
    }
}

// ====== per-fine-bucket node sort (in place) + dinv + offs ======

__global__ __launch_bounds__(256) void k_bsort(int* __restrict__ csr,
                                               const int* __restrict__ fbases,
                                               float* __restrict__ dinv,
                                               int* __restrict__ offs,
                                               int n, int ne) {
    __shared__ int s_src[CAP];
    __shared__ int h[RB];
    __shared__ int sc[RB];
    __shared__ int cur[RB];
    int bu = blockIdx.x;
    int e0 = fbases[bu], e1 = fbases[bu + 1];
    int cnt = e1 - e0;
    if (threadIdx.x < RB) h[threadIdx.x] = 0;
    __syncthreads();
    for (int i = e0 + threadIdx.x; i < e1; i += 256)
        atomicAdd(&h[(csr[i] >> 20) & 127], 1);
    __syncthreads();
    if (threadIdx.x < RB) sc[threadIdx.x] = h[threadIdx.x];
    __syncthreads();
    for (int d = 1; d < RB; d <<= 1) {
        int v = 0;
        if (threadIdx.x < RB && threadIdx.x >= d) v = sc[threadIdx.x - d];
        __syncthreads();
        if (threadIdx.x < RB) sc[threadIdx.x] += v;
        __syncthreads();
    }
    if (threadIdx.x < RB) {
        int excl = sc[threadIdx.x] - h[threadIdx.x];
        cur[threadIdx.x] = excl;
        int node = (bu << 7) + threadIdx.x;
        if (node < n) {
            dinv[node] = rsqrtf((float)(h[threadIdx.x] + 1));
            offs[node] = e0 + excl;
        }
    }
    if (bu == 0 && threadIdx.x == 0) offs[n] = ne;
    __syncthreads();
    for (int i = e0 + threadIdx.x; i < e1; i += 256) {
        int p = csr[i];
        int pos = atomicAdd(&cur[(p >> 20) & 127], 1);
        s_src[pos] = p & 0xFFFFF;
    }
    __syncthreads();
    for (int j = threadIdx.x; j < cnt; j += 256)
        csr[e0 + j] = s_src[j];
}

// ====== layer 1 linear (pre-scaled, bf16 out): h1s = bf16((x @ W1) * dinv) ======

__global__ __launch_bounds__(256) void k_gemm1(const float* __restrict__ x,
                                               const float* __restrict__ W1,
                                               const float* __restrict__ dinv,
                                               unsigned* __restrict__ h1s, int n) {
    __shared__ float Ws[F_IN * F_HID];   // 8 KB
    __shared__ float xs[16][F_IN + 1];   // 8.3 KB
    __shared__ float ys[16][17];         // 1.1 KB
    for (int i = threadIdx.x; i < F_IN * F_HID; i += 256) Ws[i] = W1[i];
    int node0 = blockIdx.x * 16;
    for (int i = threadIdx.x; i < 16 * F_IN; i += 256) {
        int r = i >> 7, c = i & 127;
        int node = node0 + r;
        xs[r][c] = (node < n) ? x[(size_t)node * F_IN + c] : 0.f;
    }
    __syncthreads();
    int r = threadIdx.x >> 4, f = threadIdx.x & 15;
    int node = node0 + r;
    float acc = 0.f;
    if (node < n) {
#pragma unroll
        for (int k = 0; k < F_IN; ++k) acc = fmaf(xs[r][k], Ws[k * F_HID + f], acc);
        acc *= dinv[node];
    }
    ys[r][f] = acc;
    __syncthreads();
    if (threadIdx.x < 128) {
        int rr = threadIdx.x >> 3, w = threadIdx.x & 7;
        int nd = node0 + rr;
        if (nd < n)
            h1s[(size_t)nd * 8 + w] = bpack2(ys[rr][2 * w], ys[rr][2 * w + 1]);
    }
}

// ====== aggregation layer 1: wave/node, 16 edge-slots x 4 chunks (uint2 = 4 bf16) ======
// h1s2 = bf16( relu((sum_nb h1s[s] + h1s[node]) * dinv + b1) * dinv )

__global__ __launch_bounds__(256) void k_agg1(const int* __restrict__ csr,
                                              const int* __restrict__ offs,
                                              const float* __restrict__ dinv,
                                              const unsigned* __restrict__ h1s,
                                              const float* __restrict__ b1,
                                              unsigned* __restrict__ h1s2, int n) {
    int node = blockIdx.x * 4 + (threadIdx.x >> 6);
    if (node >= n) return;
    int lane = threadIdx.x & 63;
    int e = lane & 15, c = lane >> 4;
    int off = offs[node], end = offs[node + 1];
    const uint2* h2 = (const uint2*)h1s;
    float a0 = 0.f, a1 = 0.f, a2 = 0.f, a3 = 0.f;
    int i = off + e;
    for (; i + 16 < end; i += 32) {
        int sA = csr[i], sB = csr[i + 16];
        uint2 vA = h2[(size_t)sA * 4 + c];
        uint2 vB = h2[(size_t)sB * 4 + c];
        a0 += blo(vA.x) + blo(vB.x);
        a1 += bhi(vA.x) + bhi(vB.x);
        a2 += blo(vA.y) + blo(vB.y);
        a3 += bhi(vA.y) + bhi(vB.y);
    }
    if (i < end) {
        uint2 v = h2[(size_t)csr[i] * 4 + c];
        a0 += blo(v.x); a1 += bhi(v.x); a2 += blo(v.y); a3 += bhi(v.y);
    }
#pragma unroll
    for (int m = 1; m <= 8; m <<= 1) {
        a0 += __shfl_xor(a0, m); a1 += __shfl_xor(a1, m);
        a2 += __shfl_xor(a2, m); a3 += __shfl_xor(a3, m);
    }
    if (e == 0) {
        float dd = dinv[node];
        uint2 sv = h2[(size_t)node * 4 + c];
        float v0 = (a0 + blo(sv.x)) * dd + b1[c * 4 + 0];
        float v1 = (a1 + bhi(sv.x)) * dd + b1[c * 4 + 1];
        float v2 = (a2 + blo(sv.y)) * dd + b1[c * 4 + 2];
        float v3 = (a3 + bhi(sv.y)) * dd + b1[c * 4 + 3];
        v0 = fmaxf(v0, 0.f) * dd; v1 = fmaxf(v1, 0.f) * dd;
        v2 = fmaxf(v2, 0.f) * dd; v3 = fmaxf(v3, 0.f) * dd;
        uint2 o; o.x = bpack2(v0, v1); o.y = bpack2(v2, v3);
        ((uint2*)h1s2)[(size_t)node * 4 + c] = o;
    }
}

// ====== aggregation layer 2 + fused W2 + bias + log_softmax ======

__global__ __launch_bounds__(256) void k_agg2(const int* __restrict__ csr,
                                              const int* __restrict__ offs,
                                              const float* __restrict__ dinv,
                                              const unsigned* __restrict__ h1s2,
                                              const float* __restrict__ W2,
                                              const float* __restrict__ b2,
                                              float* __restrict__ out, int n) {
    __shared__ float Ws[16][12];   // padded rows (cols 10,11 = 0)
    __shared__ float bs[N_CLS];
    if (threadIdx.x < 160) Ws[threadIdx.x / 10][threadIdx.x % 10] = W2[threadIdx.x];
    if (threadIdx.x >= 160 && threadIdx.x < 192) {
        int t = threadIdx.x - 160;
        Ws[t >> 1][10 + (t & 1)] = 0.f;
    }
    if (threadIdx.x >= 192 && threadIdx.x < 192 + N_CLS) bs[threadIdx.x - 192] = b2[threadIdx.x - 192];
    __syncthreads();
    int node = blockIdx.x * 4 + (threadIdx.x >> 6);
    if (node >= n) return;
    int lane = threadIdx.x & 63;
    int e = lane & 15, c = lane >> 4;
    int off = offs[node], end = offs[node + 1];
    const uint2* h2 = (const uint2*)h1s2;
    float a0 = 0.f, a1 = 0.f, a2 = 0.f, a3 = 0.f;
    int i = off + e;
    for (; i + 16 < end; i += 32) {
        int sA = csr[i], sB = csr[i + 16];
        uint2 vA = h2[(size_t)sA * 4 + c];
        uint2 vB = h2[(size_t)sB * 4 + c];
        a0 += blo(vA.x) + blo(vB.x);
        a1 += bhi(vA.x) + bhi(vB.x);
        a2 += blo(vA.y) + blo(vB.y);
        a3 += bhi(vA.y) + bhi(vB.y);
    }
    if (i < end) {
        uint2 v = h2[(size_t)csr[i] * 4 + c];
        a0 += blo(v.x); a1 += bhi(v.x); a2 += blo(v.y); a3 += bhi(v.y);
    }
#pragma unroll
    for (int m = 1; m <= 8; m <<= 1) {
        a0 += __shfl_xor(a0, m); a1 += __shfl_xor(a1, m);
        a2 += __shfl_xor(a2, m); a3 += __shfl_xor(a3, m);
    }
    // all 16 lanes of chunk c hold feature sums 4c..4c+3
    float dd = dinv[node];
    uint2 sv = h2[(size_t)node * 4 + c];
    float g0 = (a0 + blo(sv.x)) * dd;
    float g1 = (a1 + bhi(sv.x)) * dd;
    float g2 = (a2 + blo(sv.y)) * dd;
    float g3 = (a3 + bhi(sv.y)) * dd;
    // partial logits over this chunk's 4 features (padded to 12 lanes of W)
    float4 l0, l1, l2;
    {
        const float4* w0 = (const float4*)Ws[c * 4 + 0];
        const float4* w1 = (const float4*)Ws[c * 4 + 1];
        const float4* w2 = (const float4*)Ws[c * 4 + 2];
        const float4* w3 = (const float4*)Ws[c * 4 + 3];
        float4 A, B;
        A = w0[0]; B = w1[0];
        l0.x = g0 * A.x + g1 * B.x; l0.y = g0 * A.y + g1 * B.y;
        l0.z = g0 * A.z + g1 * B.z; l0.w = g0 * A.w + g1 * B.w;
        A = w0[1]; B = w1[1];
        l1.x = g0 * A.x + g1 * B.x; l1.y = g0 * A.y + g1 * B.y;
        l1.z = g0 * A.z + g1 * B.z; l1.w = g0 * A.w + g1 * B.w;
        A = w0[2]; B = w1[2];
        l2.x = g0 * A.x + g1 * B.x; l2.y = g0 * A.y + g1 * B.y;
        l2.z = g0 * A.z + g1 * B.z; l2.w = g0 * A.w + g1 * B.w;
        A = w2[0]; B = w3[0];
        l0.x += g2 * A.x + g3 * B.x; l0.y += g2 * A.y + g3 * B.y;
        l0.z += g2 * A.z + g3 * B.z; l0.w += g2 * A.w + g3 * B.w;
        A = w2[1]; B = w3[1];
        l1.x += g2 * A.x + g3 * B.x; l1.y += g2 * A.y + g3 * B.y;
        l1.z += g2 * A.z + g3 * B.z; l1.w += g2 * A.w + g3 * B.w;
        A = w2[2]; B = w3[2];
        l2.x += g2 * A.x + g3 * B.x; l2.y += g2 * A.y + g3 * B.y;
        l2.z += g2 * A.z + g3 * B.z; l2.w += g2 * A.w + g3 * B.w;
    }
    // merge the 4 chunks: lanes differing in bits 4,5 hold other chunks
#pragma unroll
    for (int m = 16; m <= 32; m <<= 1) {
        l0.x += __shfl_xor(l0.x, m); l0.y += __shfl_xor(l0.y, m);
        l0.z += __shfl_xor(l0.z, m); l0.w += __shfl_xor(l0.w, m);
        l1.x += __shfl_xor(l1.x, m); l1.y += __shfl_xor(l1.y, m);
        l1.z += __shfl_xor(l1.z, m); l1.w += __shfl_xor(l1.w, m);
        l2.x += __shfl_xor(l2.x, m); l2.y += __shfl_xor(l2.y, m);
    }
    float c0 = l0.x + bs[0], c1 = l0.y + bs[1], c2 = l0.z + bs[2], c3 = l0.w + bs[3];
    float c4 = l1.x + bs[4], c5 = l1.y + bs[5], c6 = l1.z + bs[6], c7 = l1.w + bs[7];
    float c8 = l2.x + bs[8], c9 = l2.y + bs[9];
    float m1 = fmaxf(fmaxf(fmaxf(c0, c1), fmaxf(c2, c3)), fmaxf(fmaxf(c4, c5), fmaxf(c6, c7)));
    float mm = fmaxf(m1, fmaxf(c8, c9));
    float sum = __expf(c0 - mm) + __expf(c1 - mm) + __expf(c2 - mm) + __expf(c3 - mm) +
                __expf(c4 - mm) + __expf(c5 - mm) + __expf(c6 - mm) + __expf(c7 - mm) +
                __expf(c8 - mm) + __expf(c9 - mm);
    float lse = mm + __logf(sum);
    if (lane < N_CLS) {
        float r = c0;
        r = (lane == 1) ? c1 : r; r = (lane == 2) ? c2 : r;
        r = (lane == 3) ? c3 : r; r = (lane == 4) ? c4 : r;
        r = (lane == 5) ? c5 : r; r = (lane == 6) ? c6 : r;
        r = (lane == 7) ? c7 : r; r = (lane == 8) ? c8 : r;
        r = (lane == 9) ? c9 : r;
        out[(size_t)node * N_CLS + lane] = r - lse;
    }
}

extern "C" void kernel_launch(void* const* d_in, const int* in_sizes, int n_in,
                              void* d_out, int out_size, void* d_ws, size_t ws_size,
                              hipStream_t stream) {
    const float* x  = (const float*)d_in[0];
    const int*   ei = (const int*)d_in[1];
    const float* W1 = (const float*)d_in[2];
    const float* b1 = (const float*)d_in[3];
    const float* W2 = (const float*)d_in[4];
    const float* b2 = (const float*)d_in[5];
    float* out = (float*)d_out;

    const int n  = in_sizes[0] / F_IN;   // 100000
    const int ne = in_sizes[1] / 2;      // 6400000
    const int* src = ei;
    const int* dst = ei + ne;

    const int nbc = (n + (1 << SH_C) - 1) >> SH_C;   // 98
    const int nfb = nbc * 8;                          // 784
    const int nt  = (ne + TILE - 1) / TILE;           // 391

    char* ws = (char*)d_ws;
    size_t off = 0;
    auto carve = [&](size_t bytes) -> void* {
        void* p = ws + off;
        off += (bytes + 255) & ~(size_t)255;
        return p;
    };
    int*      th     = (int*)     carve((size_t)nt * nbc * 4);
    int*      ftot   = (int*)     carve((size_t)nfb * 4);
    int*      fbases = (int*)     carve((size_t)(nfb + 1) * 4);
    float*    dinv   = (float*)   carve((size_t)n * 4);
    int*      csr    = (int*)     carve((size_t)ne * 4);       // 25.6 MB
    int*      csr2   = (int*)     carve((size_t)ne * 4);       // 25.6 MB
    int*      offsA  = (int*)     carve((size_t)(n + 1) * 4);
    unsigned* h1s    = (unsigned*)carve((size_t)n * 8 * 4);    // bf16 x16 = 3.2 MB
    unsigned* h1s2   = (unsigned*)carve((size_t)n * 8 * 4);    // 3.2 MB
    (void)ws_size;

    hipMemsetAsync(ftot, 0, (size_t)nfb * 4, stream);

    k_hist2<<<nt, 256, 0, stream>>>(dst, th, ftot, ne, nbc, nfb);
    k_colscan<<<nbc, 256, 0, stream>>>(th, nt, nbc);
    k_bscan<<<1, 1024, 0, stream>>>(ftot, fbases, nfb);
    k_tilescatter<<<nt, 256, 0, stream>>>(src, dst, th, fbases, csr, ne, nbc);
    k_split<<<nbc, 1024, 0, stream>>>(csr, fbases, csr2, nbc);
    k_bsort<<<nfb, 256, 0, stream>>>(csr2, fbases, dinv, offsA, n, ne);

    k_gemm1<<<(n + 15) / 16, 256, 0, stream>>>(x, W1, dinv, h1s, n);
    k_agg1<<<(n + 3) / 4, 256, 0, stream>>>(csr2, offsA, dinv, h1s, b1, h1s2, n);
    k_agg2<<<(n + 3) / 4, 256, 0, stream>>>(csr2, offsA, dinv, h1s2, W2, b2, out, n);
}